// Round 7
// baseline (105.326 us; speedup 1.0000x reference)
//
#include <hip/hip_runtime.h>

#define H     256
#define BM    128
#define NTHR  512
#define LDK2  264    // 256 + 8 pad (ushorts): row stride 528 B

typedef __attribute__((ext_vector_type(4))) float f32x4;
typedef __attribute__((ext_vector_type(8))) short bf16x8;

__device__ __forceinline__ ushort f2bf(float f) {
    union { float f; unsigned u; } v; v.f = f;
    unsigned u = v.u;
    unsigned r = (u + 0x7fffu + ((u >> 16) & 1u)) >> 16;
    return (ushort)r;
}
__device__ __forceinline__ float bf2f(ushort h) {
    union { unsigned u; float f; } v; v.u = ((unsigned)h) << 16;
    return v.f;
}
__device__ __forceinline__ float sigmoid_f(float x) {
    return __builtin_amdgcn_rcpf(1.0f + __expf(-x));
}
__device__ __forceinline__ float tanh_f(float x) {
    float ax = fabsf(x);
    float e  = __expf(-2.0f * ax);
    float t  = (1.0f - e) * __builtin_amdgcn_rcpf(1.0f + e);
    return copysignf(t, x);
}

// --- weight prep: f32 [k][n] -> bf16 panels [n][k] in d_ws ---
// rows 0..255 = r cols (k<256: W_r, k>=256: U_r); 256..511 = z; 512..767 = h
__global__ void prep_w(const float* __restrict__ Wr, const float* __restrict__ Wz,
                       const float* __restrict__ Wh, const float* __restrict__ Ur,
                       const float* __restrict__ Uz, const float* __restrict__ Uh,
                       ushort* __restrict__ P)
{
    const int k  = blockIdx.x;          // 0..511
    const int kk = k & 255;
    const bool hi = k >= 256;
    for (int n = threadIdx.x; n < 768; n += 256) {
        float v;
        if (n < 256)      v = (hi ? Ur : Wr)[kk * 256 + n];
        else if (n < 512) v = (hi ? Uz : Wz)[kk * 256 + (n - 256)];
        else              v = (hi ? Uh : Wh)[kk * 256 + (n - 512)];
        P[(size_t)n * 512 + k] = f2bf(v);
    }
}

#define MFMA(a, b, c) __builtin_amdgcn_mfma_f32_16x16x32_bf16((a), (b), (c), 0, 0, 0)

// one 16x16x32 k-step over r|z accumulators
#define RZ_STEP(SB, KOFF, K0) do {                                            \
    bf16x8 bR_[2], bZ_[2], af_[8];                                            \
    _Pragma("unroll") for (int j_ = 0; j_ < 2; ++j_) {                        \
        bR_[j_] = *(const bf16x8*)(pBr + (size_t)j_ * 16 * 512 + (KOFF) + (K0)); \
        bZ_[j_] = *(const bf16x8*)(pBz + (size_t)j_ * 16 * 512 + (KOFF) + (K0)); \
    }                                                                         \
    _Pragma("unroll") for (int i_ = 0; i_ < 8; ++i_)                          \
        af_[i_] = *(const bf16x8*)&SB[(i_ * 16 + l15) * LDK2 + (K0) + kq * 8];\
    _Pragma("unroll") for (int j_ = 0; j_ < 2; ++j_)                          \
    _Pragma("unroll") for (int i_ = 0; i_ < 8; ++i_) {                        \
        aR[i_][j_] = MFMA(af_[i_], bR_[j_], aR[i_][j_]);                      \
        aZ[i_][j_] = MFMA(af_[i_], bZ_[j_], aZ[i_][j_]);                      \
    }                                                                         \
} while (0)

#define H_STEP(SB, KOFF, K0) do {                                             \
    bf16x8 bH_[2], af_[8];                                                    \
    _Pragma("unroll") for (int j_ = 0; j_ < 2; ++j_)                          \
        bH_[j_] = *(const bf16x8*)(pBh + (size_t)j_ * 16 * 512 + (KOFF) + (K0)); \
    _Pragma("unroll") for (int i_ = 0; i_ < 8; ++i_)                          \
        af_[i_] = *(const bf16x8*)&SB[(i_ * 16 + l15) * LDK2 + (K0) + kq * 8];\
    _Pragma("unroll") for (int j_ = 0; j_ < 2; ++j_)                          \
    _Pragma("unroll") for (int i_ = 0; i_ < 8; ++i_)                          \
        aH[i_][j_] = MFMA(af_[i_], bH_[j_], aH[i_][j_]);                      \
} while (0)

// staging pipeline: 4-f32x4 chunks, issue early / commit late
#define LOADJ(JV, CI) do {                                                    \
    _Pragma("unroll") for (int i_ = 0; i_ < 4; ++i_) {                        \
        const int c_ = tid + ((CI) * 4 + i_) * NTHR;                          \
        JV[i_] = *(const f32x4*)(joint + (r0 + (c_ >> 6)) * H + (c_ & 63) * 4); \
    }                                                                         \
} while (0)

#define COMMITJ(JV, CI) do {                                                  \
    _Pragma("unroll") for (int i_ = 0; i_ < 4; ++i_) {                        \
        const int c_ = tid + ((CI) * 4 + i_) * NTHR;                          \
        ushort4 w_;                                                           \
        w_.x = f2bf(JV[i_][0]); w_.y = f2bf(JV[i_][1]);                       \
        w_.z = f2bf(JV[i_][2]); w_.w = f2bf(JV[i_][3]);                       \
        *(ushort4*)&sb1[(c_ >> 6) * LDK2 + (c_ & 63) * 4] = w_;               \
    }                                                                         \
} while (0)

__global__ __launch_bounds__(NTHR, 2)
void gru_main(const float* __restrict__ joint, const float* __restrict__ mgn,
              const ushort* __restrict__ P,
              const float* __restrict__ br_, const float* __restrict__ bz_,
              const float* __restrict__ bh_, float* __restrict__ out)
{
    __shared__ ushort sb0[BM * LDK2];   // mgn bf16 — resident for the whole kernel
    __shared__ ushort sb1[BM * LDK2];   // joint bf16 -> overwritten by a = joint*r

    const int tid  = threadIdx.x;
    const int wave = tid >> 6;          // 0..7
    const int lane = tid & 63;
    const int l15  = lane & 15;
    const int kq   = lane >> 4;         // 0..3
    const int colbase = wave * 32;
    const size_t r0 = (size_t)blockIdx.x * BM;

    const ushort* __restrict__ pBr = P + (size_t)(colbase + l15) * 512 + kq * 8;
    const ushort* __restrict__ pBz = pBr + (size_t)256 * 512;
    const ushort* __restrict__ pBh = pBr + (size_t)512 * 512;

    // --- stage 0: mgn -> sb0 (kernel head, nothing to overlap with) ---
    #pragma unroll
    for (int i = 0; i < 16; ++i) {
        const int c   = tid + i * NTHR;
        const int row = c >> 6;
        const int c4  = (c & 63) * 4;
        const f32x4 v = *(const f32x4*)(mgn + (r0 + row) * H + c4);
        ushort4 w;
        w.x = f2bf(v[0]); w.y = f2bf(v[1]); w.z = f2bf(v[2]); w.w = f2bf(v[3]);
        *(ushort4*)&sb0[row * LDK2 + c4] = w;
    }
    __syncthreads();

    f32x4 aR[8][2], aZ[8][2];
    #pragma unroll
    for (int i = 0; i < 8; ++i)
        #pragma unroll
        for (int j = 0; j < 2; ++j) {
            aR[i][j] = (f32x4){0.f, 0.f, 0.f, 0.f};
            aZ[i][j] = (f32x4){0.f, 0.f, 0.f, 0.f};
        }

    // --- phase 1, k-half 0 (mgn in sb0), joint -> sb1 staged in 4 chunks,
    //     each chunk's loads covered by ~2 MFMA clusters before commit ---
    {
        f32x4 jvA[4], jvB[4];
        LOADJ(jvA, 0);
        RZ_STEP(sb0, 0, 0);   RZ_STEP(sb0, 0, 32);
        LOADJ(jvB, 1);
        RZ_STEP(sb0, 0, 64);  RZ_STEP(sb0, 0, 96);
        COMMITJ(jvA, 0); LOADJ(jvA, 2);
        RZ_STEP(sb0, 0, 128); RZ_STEP(sb0, 0, 160);
        COMMITJ(jvB, 1); LOADJ(jvB, 3);
        RZ_STEP(sb0, 0, 192); RZ_STEP(sb0, 0, 224);
        COMMITJ(jvA, 2);
        COMMITJ(jvB, 3);
    }
    __syncthreads();

    // --- phase 1, k-half 1 (joint in sb1) ---
    #pragma unroll 4
    for (int k0 = 0; k0 < 256; k0 += 32) RZ_STEP(sb1, 256, k0);
    __syncthreads();

    // --- gates: z in regs; a = joint*r overwrites sb1 ---
    float br[2], bz[2], bh[2];
    #pragma unroll
    for (int j = 0; j < 2; ++j) {
        const int c = colbase + j * 16 + l15;
        br[j] = br_[c]; bz[j] = bz_[c]; bh[j] = bh_[c];
    }
    #pragma unroll
    for (int i = 0; i < 8; ++i)
        #pragma unroll
        for (int j = 0; j < 2; ++j)
            #pragma unroll
            for (int q = 0; q < 4; ++q) {
                const int row = i * 16 + kq * 4 + q;
                const int c   = colbase + j * 16 + l15;
                const float r = sigmoid_f(aR[i][j][q] + br[j]);
                const float hj = bf2f(sb1[row * LDK2 + c]);
                sb1[row * LDK2 + c] = f2bf(hj * r);
                aZ[i][j][q] = sigmoid_f(aZ[i][j][q] + bz[j]);
            }
    __syncthreads();

    // --- phase 2: ht = [mgn | a] @ P_h — both halves resident, no staging ---
    f32x4 aH[8][2];
    #pragma unroll
    for (int i = 0; i < 8; ++i)
        #pragma unroll
        for (int j = 0; j < 2; ++j)
            aH[i][j] = (f32x4){0.f, 0.f, 0.f, 0.f};

    #pragma unroll 4
    for (int k0 = 0; k0 < 256; k0 += 32) H_STEP(sb1, 256, k0);
    #pragma unroll 4
    for (int k0 = 0; k0 < 256; k0 += 32) H_STEP(sb0, 0, k0);

    // --- epilogue: out = ht + z*(h - ht), h re-read f32 (L3-warm) ---
    #pragma unroll
    for (int i = 0; i < 8; ++i)
        #pragma unroll
        for (int j = 0; j < 2; ++j)
            #pragma unroll
            for (int q = 0; q < 4; ++q) {
                const int row = i * 16 + kq * 4 + q;
                const int c   = colbase + j * 16 + l15;
                const float ht = tanh_f(aH[i][j][q] + bh[j]);
                const float z  = aZ[i][j][q];
                const float h  = joint[(r0 + row) * H + c];
                out[(r0 + row) * H + c] = ht + z * (h - ht);
            }
}

extern "C" void kernel_launch(void* const* d_in, const int* in_sizes, int n_in,
                              void* d_out, int out_size, void* d_ws, size_t ws_size,
                              hipStream_t stream)
{
    const float* joint = (const float*)d_in[0];
    const float* mgn   = (const float*)d_in[1];
    const float* Wr    = (const float*)d_in[2];
    const float* Wz    = (const float*)d_in[3];
    const float* Wh    = (const float*)d_in[4];
    const float* Ur    = (const float*)d_in[5];
    const float* Uz    = (const float*)d_in[6];
    const float* Uh    = (const float*)d_in[7];
    const float* br    = (const float*)d_in[8];
    const float* bz    = (const float*)d_in[9];
    const float* bh    = (const float*)d_in[10];

    ushort* P  = (ushort*)d_ws;          // 786 KB scratch
    float* out = (float*)d_out;

    prep_w<<<512, 256, 0, stream>>>(Wr, Wz, Wh, Ur, Uz, Uh, P);

    const int nrows = 65536;
    gru_main<<<nrows / BM, NTHR, 0, stream>>>(joint, mgn, P, br, bz, bh, out);
}